// Round 17
// baseline (225.266 us; speedup 1.0000x reference)
//
#include <hip/hip_runtime.h>
#include <stdint.h>

#define NN 65536
#define NE 262144

typedef __attribute__((ext_vector_type(8))) short bf16x8;
typedef __attribute__((ext_vector_type(4))) float f32x4;

__device__ __forceinline__ short f2bf(float f) {
  union { float f; uint32_t u; } v; v.f = f;
  uint32_t u = v.u + 0x7fffu + ((v.u >> 16) & 1u);
  return (short)(u >> 16);
}
__device__ __forceinline__ uint32_t cvtpk(float lo, float hi) {
  uint32_t r;
  asm("v_cvt_pk_bf16_f32 %0, %1, %2" : "=v"(r) : "v"(lo), "v"(hi));
  return r;
}

// Merged prep: eab bf16 (k<16 zero-padded), transposed bf16 weights, dst
// histogram into cnt32 (65536 counters, low contention). NO bsum atomic here —
// R15 showed 256-counter atomics serialize (prep_all 8us -> 136us).
__global__ __launch_bounds__(256) void prep_all(
    const float* __restrict__ ea, short* __restrict__ eab,
    const float* __restrict__ w1_0, const float* __restrict__ w1_1,
    const float* __restrict__ w2_0, const float* __restrict__ w2_1,
    short* __restrict__ w1t0, short* __restrict__ w1t1,
    short* __restrict__ w2t0, short* __restrict__ w2t1,
    const int* __restrict__ ei, int* __restrict__ cnt32) {
  int idx = blockIdx.x * 256 + threadIdx.x;  // grid = NE*16/256
  {
    int e = idx >> 4, k = idx & 15;
    eab[idx] = (k < 10) ? f2bf(ea[e * 10 + k]) : (short)0;
  }
  if (idx < NE) atomicAdd(&cnt32[ei[NE + idx]], 1);
  if (idx < 65536) {
    if (idx < 8192) {
      int n = idx >> 5, k = idx & 31;
      w1t0[idx] = (k < 10) ? f2bf(w1_0[k * 256 + n]) : (short)0;
      w1t1[idx] = (k < 10) ? f2bf(w1_1[k * 256 + n]) : (short)0;
    }
    if (idx < 32768) {
      int n = idx >> 8, k = idx & 255;
      w2t1[idx] = f2bf(w2_1[k * 128 + n]);
    }
    {
      int n = idx >> 8, k = idx & 255;
      w2t0[idx] = f2bf(w2_0[k * 256 + n]);
    }
  }
}

// bsum[b] = sum of cnt32[b*256 .. b*256+255]  (tree reduction, no atomics)
__global__ __launch_bounds__(256) void scan1_kernel(const int* __restrict__ cnt32,
                                                    int* __restrict__ bsum) {
  __shared__ int sd[256];
  int t = threadIdx.x, b = blockIdx.x;
  sd[t] = cnt32[b * 256 + t];
  __syncthreads();
  for (int s = 128; s > 0; s >>= 1) {
    if (t < s) sd[t] += sd[t + s];
    __syncthreads();
  }
  if (t == 0) bsum[b] = sd[0];
}

// Merged scan2+scan3: each block scans the 256-entry bsum in LDS (redundant
// per-block) + its own 256-node cnt32 chunk -> global exclusive offsets.
__global__ __launch_bounds__(256) void scan_kernel(
    const int* __restrict__ cnt32, const int* __restrict__ bsum,
    int* __restrict__ off, int* __restrict__ cursor) {
  __shared__ int sb[256];
  __shared__ int sd[256];
  int t = threadIdx.x, b = blockIdx.x;
  int idx = b * 256 + t;
  int vb = bsum[t];
  int vd = cnt32[idx];
  sb[t] = vb;
  sd[t] = vd;
  __syncthreads();
  for (int st = 1; st < 256; st <<= 1) {
    int xb = (t >= st) ? sb[t - st] : 0;
    int xd = (t >= st) ? sd[t - st] : 0;
    __syncthreads();
    sb[t] += xb;
    sd[t] += xd;
    __syncthreads();
  }
  int boffb = sb[b] - bsum[b];      // exclusive prefix of bsum at b
  int o = boffb + sd[t] - vd;       // global exclusive offset for node idx
  off[idx] = o;
  cursor[idx] = o;
  if (b == 0 && t == 0) off[65536] = NE;
}

__global__ __launch_bounds__(256) void scatter_kernel(const int* __restrict__ ei,
                                                      int* __restrict__ cursor,
                                                      int* __restrict__ eidx) {
  int e = blockIdx.x * 256 + threadIdx.x;
  int pos = atomicAdd(&cursor[ei[NE + e]], 1);
  eidx[pos] = e;
}

// ---------------- fused edge kernel: 128 edges/block, 8 waves ----------------
// SPLIT-ET variant of R16 (LDS-read-bandwidth attack): L0==L1 edge time at
// equal hB read volume showed per-CU LDS BW (~20us of 58) is the wall.
// Waves = 2 e-groups x 4 col-groups: wave (er,cg) owns 4 e-tiles x WCG cols ->
// per-ks 4 a2 LDS reads (was 8) feeding the SAME 16 MFMAs (NT2 doubled).
// w2t traffic 2x (L2-resident). bcur preload AFTER h-store (acc1/be dead; no
// boundary spill) but BEFORE barrier (latency hides under barrier wait).
// GEMM1, h-store layout, partial epilogue logic unchanged; partial slots = cg.
// Register law: acc(64 AGPR) + bcur/bnxt(16+16) + a2(16) + addr <= 128.
// OUTC=8: lanes lr / lr^8 share o (different i parity) -> __shfl_xor(m,8).
// Output: msg[e][o] f32 coalesced (no atomics).
template <int N2, int OUTC>
__global__ __launch_bounds__(512, 4) void edge_kernel(
    const float* __restrict__ x, const int* __restrict__ ei,
    const short* __restrict__ eab, const short* __restrict__ w1t,
    const float* __restrict__ b1, const short* __restrict__ w2t,
    const float* __restrict__ b2, float* __restrict__ msg) {
  constexpr int WCG = N2 / 4;                   // cols per col-group: 64 / 32
  constexpr int NT2 = WCG / 16;                 // 4 / 2
  constexpr int LOGO = (OUTC == 16) ? 4 : 3;
  constexpr int PADO = OUTC + 1;                // 17 / 9
  constexpr int PARTSZ = 4 * 128 * PADO * 4;    // 34816 / 18432 (4 cg slots)
  constexpr int XSOFF = (PARTSZ > 65536) ? PARTSZ : 65536;
  __shared__ alignas(16) char smem[XSOFF + 128 * 20 * 4];
  short* const hB = (short*)smem;               // 64 KB fragment-ordered h
  float* const partial = (float*)smem;          // overlays hB after GEMM2
  float* const xs = (float*)(smem + XSOFF);     // x[src] [128][20] f32

  const int tid = threadIdx.x;
  const int w = tid >> 6;
  const int lane = tid & 63;
  const int g = lane >> 4;
  const int lr = lane & 15;
  const int e0 = blockIdx.x * 128;
  const int er = w >> 2;   // e-group: et in [er*4, +4)
  const int cg = w & 3;    // col-group: cols [cg*WCG, +WCG)

  // ---- stage x[src] tile [128][20] f32 ----
  const int eR = tid >> 2;
  const int qR = tid & 3;
  {
    int s = ei[e0 + eR];
    float4 v = *(const float4*)(x + (size_t)s * 16 + qR * 4);
    *(float4*)(xs + eR * 20 + qR * 4) = v;
  }

  // ---- GEMM1 frags: wave w computes h k-rows [w*32, +32) for all 128 edges
  bf16x8 aw[2];
#pragma unroll
  for (int ml = 0; ml < 2; ++ml)
    aw[ml] = *(const bf16x8*)(w1t + ((w * 2 + ml) * 16 + lr) * 32 + g * 8);
  bf16x8 be[8];
#pragma unroll
  for (int et = 0; et < 8; ++et) {
    if (g < 2)
      be[et] = *(const bf16x8*)(eab + (size_t)(e0 + et * 16 + lr) * 16 + g * 8);
    else
      be[et] = (bf16x8){0, 0, 0, 0, 0, 0, 0, 0};
  }

  // ---- GEMM1: acc1[ml][et] -> h[k=(w*2+ml)*16+g*4+r][e=et*16+lr] ----
  f32x4 acc1[2][8];
#pragma unroll
  for (int ml = 0; ml < 2; ++ml)
#pragma unroll
    for (int et = 0; et < 8; ++et) acc1[ml][et] = (f32x4){0.f, 0.f, 0.f, 0.f};
#pragma unroll
  for (int et = 0; et < 8; ++et)
#pragma unroll
    for (int ml = 0; ml < 2; ++ml)
      acc1[ml][et] = __builtin_amdgcn_mfma_f32_16x16x32_bf16(aw[ml], be[et], acc1[ml][et], 0, 0, 0);

  // ---- h = relu(+b1) -> hL fragment-ordered (ks = w for this wave) ----
  // store k = (w*2+ml)*16+g*4+r  ->  reader (ks=w, rg=ml*2+(g>>1), j=(g&1)*4+r)
#pragma unroll
  for (int ml = 0; ml < 2; ++ml) {
    const int K16 = w * 2 + ml;
    const int rg = ml * 2 + (g >> 1);
    const int j0 = (g & 1) * 4;
    float4 bb1 = *(const float4*)(b1 + K16 * 16 + g * 4);
#pragma unroll
    for (int et = 0; et < 8; ++et) {
      float v0 = fmaxf(acc1[ml][et][0] + bb1.x, 0.f);
      float v1 = fmaxf(acc1[ml][et][1] + bb1.y, 0.f);
      float v2 = fmaxf(acc1[ml][et][2] + bb1.z, 0.f);
      float v3 = fmaxf(acc1[ml][et][3] + bb1.w, 0.f);
      int2 pw; pw.x = (int)cvtpk(v0, v1); pw.y = (int)cvtpk(v2, v3);
      *(int2*)(hB + ((et * 8 + w) * 64 + rg * 16 + lr) * 8 + j0) = pw;
    }
  }

  // ---- GEMM2 B-frags for ks=0: issue after h-store (acc1/be dead -> no
  //      boundary spill), before barrier (latency hides under barrier wait) ----
  bf16x8 bcur[NT2];
#pragma unroll
  for (int nt = 0; nt < NT2; ++nt) {
    int colo = cg * WCG + nt * 16 + lr;
    bcur[nt] = *(const bf16x8*)(w2t + colo * 256 + g * 8);
  }
  __syncthreads();

  // ---- GEMM2: acc[mt][nt], et = er*4+mt; A = hL (linear-lane reads,
  //      conflict-free, 4 per ks), B = w2t depth-1 prefetch (4 per ks) ----
  f32x4 acc[4][NT2];
#pragma unroll
  for (int mt = 0; mt < 4; ++mt)
#pragma unroll
    for (int nt = 0; nt < NT2; ++nt) acc[mt][nt] = (f32x4){0.f, 0.f, 0.f, 0.f};
#pragma unroll
  for (int ks = 0; ks < 8; ++ks) {
    bf16x8 bnxt[NT2];
    if (ks < 7) {
#pragma unroll
      for (int nt = 0; nt < NT2; ++nt) {
        int colo = cg * WCG + nt * 16 + lr;
        bnxt[nt] = *(const bf16x8*)(w2t + colo * 256 + (ks + 1) * 32 + g * 8);
      }
    }
    bf16x8 a2[4];
#pragma unroll
    for (int mt = 0; mt < 4; ++mt)
      a2[mt] = *(const bf16x8*)(hB + (((er * 4 + mt) * 8 + ks) * 64 + lane) * 8);
#pragma unroll
    for (int nt = 0; nt < NT2; ++nt)
#pragma unroll
      for (int mt = 0; mt < 4; ++mt)
        acc[mt][nt] = __builtin_amdgcn_mfma_f32_16x16x32_bf16(a2[mt], bcur[nt], acc[mt][nt], 0, 0, 0);
    if (ks < 7) {
#pragma unroll
      for (int nt = 0; nt < NT2; ++nt) bcur[nt] = bnxt[nt];
    }
  }
  __syncthreads();  // all hL reads done -> partial may overlay

  // ---- epilogue: bilinear in registers -> partial[slot=cg][e][o] ----
  {
    const int o = lr & (OUTC - 1);
    float b2c[NT2];
    int iv[NT2];
#pragma unroll
    for (int nt = 0; nt < NT2; ++nt) {
      int colo = cg * WCG + nt * 16 + lr;
      b2c[nt] = b2[colo];
      iv[nt] = colo >> LOGO;
    }
#pragma unroll
    for (int mt = 0; mt < 4; ++mt)
#pragma unroll
      for (int r = 0; r < 4; ++r) {
        int e = (er * 4 + mt) * 16 + g * 4 + r;
        float m = 0.f;
#pragma unroll
        for (int nt = 0; nt < NT2; ++nt)
          m += (acc[mt][nt][r] + b2c[nt]) * xs[e * 20 + iv[nt]];
        if (OUTC == 8) m += __shfl_xor(m, 8, 64);  // sum lr-halves (i parity)
        partial[((size_t)cg * 128 + e) * PADO + o] = m;
      }
  }
  __syncthreads();

  // ---- cross-cg reduce -> coalesced msg store ----
  if (qR * 4 < OUTC) {
    float v[4];
#pragma unroll
    for (int j = 0; j < 4; ++j) {
      int o = qR * 4 + j;
      float s = 0.f;
#pragma unroll
      for (int sl = 0; sl < 4; ++sl) s += partial[((size_t)sl * 128 + eR) * PADO + o];
      v[j] = s;
    }
    *(float4*)(msg + (size_t)(e0 + eR) * OUTC + qR * 4) =
        (float4){v[0], v[1], v[2], v[3]};
  }
}

// x_out = relu(gather-mean(msg over CSR) + x_in @ root + bias)
template <int OUTC>
__global__ __launch_bounds__(256) void node_csr(
    const float* __restrict__ xin, const float* __restrict__ msg,
    const int* __restrict__ off, const int* __restrict__ eidx,
    const float* __restrict__ root, const float* __restrict__ bias,
    float* __restrict__ xout) {
  constexpr int Q = OUTC / 4;  // 4 / 2
  __shared__ float rootL[16 * OUTC];
  __shared__ float biasL[OUTC];
  int tid = threadIdx.x;
  if (tid < 16 * OUTC) rootL[tid] = root[tid];
  if (tid < OUTC) biasL[tid] = bias[tid];
  __syncthreads();
  int n = blockIdx.x * (256 / Q) + tid / Q;
  int q = tid & (Q - 1);
  int o0 = off[n], o1 = off[n + 1];
  const float4* msg4 = (const float4*)msg;
  float s[4] = {0.f, 0.f, 0.f, 0.f};
  for (int i = o0; i < o1; ++i) {
    int e = eidx[i];
    float4 v = msg4[(size_t)e * Q + q];
    s[0] += v.x; s[1] += v.y; s[2] += v.z; s[3] += v.w;
  }
  float inv = 1.0f / fmaxf((float)(o1 - o0), 1.0f);
  float xi[16];
#pragma unroll
  for (int i = 0; i < 4; ++i) {
    float4 v = ((const float4*)(xin + (size_t)n * 16))[i];
    xi[4 * i] = v.x; xi[4 * i + 1] = v.y; xi[4 * i + 2] = v.z; xi[4 * i + 3] = v.w;
  }
  float r[4];
#pragma unroll
  for (int j = 0; j < 4; ++j) {
    int o = q * 4 + j;
    float a = s[j] * inv + biasL[o];
#pragma unroll
    for (int i = 0; i < 16; ++i) a += xi[i] * rootL[i * OUTC + o];
    r[j] = fmaxf(a, 0.f);
  }
  *(float4*)(xout + (size_t)n * OUTC + q * 4) = (float4){r[0], r[1], r[2], r[3]};
}

__global__ __launch_bounds__(256) void final_kernel(
    const float* __restrict__ x2, const int* __restrict__ ei,
    const float* __restrict__ fcw, const float* __restrict__ fcb,
    float* __restrict__ out) {
  int e = blockIdx.x * 256 + threadIdx.x;
  int s = ei[e], d = ei[NE + e];
  float acc = fcb[0];
  const float* xsr = x2 + (size_t)s * 8;
  const float* xdr = x2 + (size_t)d * 8;
#pragma unroll
  for (int c = 0; c < 8; ++c) acc += xsr[c] * fcw[c];
#pragma unroll
  for (int c = 0; c < 8; ++c) acc += xdr[c] * fcw[8 + c];
  out[e] = 1.0f / (1.0f + __expf(-acc));
}

extern "C" void kernel_launch(void* const* d_in, const int* in_sizes, int n_in,
                              void* d_out, int out_size, void* d_ws, size_t ws_size,
                              hipStream_t stream) {
  const float* x      = (const float*)d_in[0];
  const int*   ei     = (const int*)d_in[1];
  const float* ea     = (const float*)d_in[2];
  const float* w1_0   = (const float*)d_in[3];
  const float* b1_0   = (const float*)d_in[4];
  const float* w2_0   = (const float*)d_in[5];
  const float* b2_0   = (const float*)d_in[6];
  const float* root_0 = (const float*)d_in[7];
  const float* bias_0 = (const float*)d_in[8];
  const float* w1_1   = (const float*)d_in[9];
  const float* b1_1   = (const float*)d_in[10];
  const float* w2_1   = (const float*)d_in[11];
  const float* b2_1   = (const float*)d_in[12];
  const float* root_1 = (const float*)d_in[13];
  const float* bias_1 = (const float*)d_in[14];
  const float* fc_w   = (const float*)d_in[15];
  const float* fc_b   = (const float*)d_in[16];
  float* out = (float*)d_out;

  char* ws = (char*)d_ws;
  int*   off    = (int*)(ws);                          // 65537 ints
  int*   cursor = (int*)(ws + (512u << 10));           // 256KB (doubles as cnt32)
  int*   bsum   = (int*)(ws + (768u << 10));           // 1KB
  short* w1t0   = (short*)(ws + (1u << 20) + 16384);
  short* w1t1   = w1t0 + 8192;
  short* w2t0   = w1t1 + 8192;
  short* w2t1   = w2t0 + 65536;
  float* x1     = (float*)(ws + (2u << 20));           // 4 MB
  float* x2     = (float*)(ws + (6u << 20));           // 2 MB
  int*   eidx   = (int*)(ws + (8u << 20));             // 1 MB
  short* eab    = (short*)(ws + (9u << 20));           // 8 MB
  float* msg    = (float*)(ws + (17u << 20));          // 16 MB (shared L0/L1)

  int* cnt32 = cursor;  // histogram; scan_kernel rewrites cursor = off

  hipMemsetAsync(cnt32, 0, (size_t)NN * 4, stream);
  prep_all<<<NE * 16 / 256, 256, 0, stream>>>(ea, eab, w1_0, w1_1, w2_0, w2_1,
                                              w1t0, w1t1, w2t0, w2t1, ei, cnt32);
  scan1_kernel<<<256, 256, 0, stream>>>(cnt32, bsum);
  scan_kernel<<<256, 256, 0, stream>>>(cnt32, bsum, off, cursor);
  scatter_kernel<<<NE / 256, 256, 0, stream>>>(ei, cursor, eidx);

  edge_kernel<256, 16><<<NE / 128, 512, 0, stream>>>(
      x, ei, eab, w1t0, b1_0, w2t0, b2_0, msg);
  node_csr<16><<<NN * 4 / 256, 256, 0, stream>>>(x, msg, off, eidx, root_0, bias_0, x1);
  edge_kernel<128, 8><<<NE / 128, 512, 0, stream>>>(
      x1, ei, eab, w1t1, b1_1, w2t1, b2_1, msg);
  node_csr<8><<<NN * 2 / 256, 256, 0, stream>>>(x1, msg, off, eidx, root_1, bias_1, x2);
  final_kernel<<<NE / 256, 256, 0, stream>>>(x2, ei, fc_w, fc_b, out);
}

// Round 18
// 203.332 us; speedup vs baseline: 1.1079x; 1.1079x over previous
//
#include <hip/hip_runtime.h>
#include <stdint.h>

#define NN 65536
#define NE 262144

typedef __attribute__((ext_vector_type(8))) short bf16x8;
typedef __attribute__((ext_vector_type(4))) float f32x4;
typedef __attribute__((ext_vector_type(16))) float f32x16;

__device__ __forceinline__ short f2bf(float f) {
  union { float f; uint32_t u; } v; v.f = f;
  uint32_t u = v.u + 0x7fffu + ((v.u >> 16) & 1u);
  return (short)(u >> 16);
}
__device__ __forceinline__ uint32_t cvtpk(float lo, float hi) {
  uint32_t r;
  asm("v_cvt_pk_bf16_f32 %0, %1, %2" : "=v"(r) : "v"(lo), "v"(hi));
  return r;
}

// Merged prep: eab bf16 (k<16 zero-padded), transposed bf16 weights, dst
// histogram into cnt32 (65536 counters, low contention; R15: 256-counter
// atomics serialize).
__global__ __launch_bounds__(256) void prep_all(
    const float* __restrict__ ea, short* __restrict__ eab,
    const float* __restrict__ w1_0, const float* __restrict__ w1_1,
    const float* __restrict__ w2_0, const float* __restrict__ w2_1,
    short* __restrict__ w1t0, short* __restrict__ w1t1,
    short* __restrict__ w2t0, short* __restrict__ w2t1,
    const int* __restrict__ ei, int* __restrict__ cnt32) {
  int idx = blockIdx.x * 256 + threadIdx.x;  // grid = NE*16/256
  {
    int e = idx >> 4, k = idx & 15;
    eab[idx] = (k < 10) ? f2bf(ea[e * 10 + k]) : (short)0;
  }
  if (idx < NE) atomicAdd(&cnt32[ei[NE + idx]], 1);
  if (idx < 65536) {
    if (idx < 8192) {
      int n = idx >> 5, k = idx & 31;
      w1t0[idx] = (k < 10) ? f2bf(w1_0[k * 256 + n]) : (short)0;
      w1t1[idx] = (k < 10) ? f2bf(w1_1[k * 256 + n]) : (short)0;
    }
    if (idx < 32768) {
      int n = idx >> 8, k = idx & 255;
      w2t1[idx] = f2bf(w2_1[k * 128 + n]);
    }
    {
      int n = idx >> 8, k = idx & 255;
      w2t0[idx] = f2bf(w2_0[k * 256 + n]);
    }
  }
}

// bsum[b] = sum of cnt32[b*256 .. +255]  (tree reduction, no atomics)
__global__ __launch_bounds__(256) void scan1_kernel(const int* __restrict__ cnt32,
                                                    int* __restrict__ bsum) {
  __shared__ int sd[256];
  int t = threadIdx.x, b = blockIdx.x;
  sd[t] = cnt32[b * 256 + t];
  __syncthreads();
  for (int s = 128; s > 0; s >>= 1) {
    if (t < s) sd[t] += sd[t + s];
    __syncthreads();
  }
  if (t == 0) bsum[b] = sd[0];
}

// Merged scan2+scan3 -> global exclusive offsets.
__global__ __launch_bounds__(256) void scan_kernel(
    const int* __restrict__ cnt32, const int* __restrict__ bsum,
    int* __restrict__ off, int* __restrict__ cursor) {
  __shared__ int sb[256];
  __shared__ int sd[256];
  int t = threadIdx.x, b = blockIdx.x;
  int idx = b * 256 + t;
  int vb = bsum[t];
  int vd = cnt32[idx];
  sb[t] = vb;
  sd[t] = vd;
  __syncthreads();
  for (int st = 1; st < 256; st <<= 1) {
    int xb = (t >= st) ? sb[t - st] : 0;
    int xd = (t >= st) ? sd[t - st] : 0;
    __syncthreads();
    sb[t] += xb;
    sd[t] += xd;
    __syncthreads();
  }
  int boffb = sb[b] - bsum[b];
  int o = boffb + sd[t] - vd;
  off[idx] = o;
  cursor[idx] = o;
  if (b == 0 && t == 0) off[65536] = NE;
}

__global__ __launch_bounds__(256) void scatter_kernel(const int* __restrict__ ei,
                                                      int* __restrict__ cursor,
                                                      int* __restrict__ eidx) {
  int e = blockIdx.x * 256 + threadIdx.x;
  int pos = atomicAdd(&cursor[ei[NE + e]], 1);
  eidx[pos] = e;
}

// ---------------- fused edge kernel: 128 edges/block, 8 waves ----------------
// 32x32x16 GEMM2 variant (LDS-BW attack at R16's register budget):
//   GEMM1 (16x16x32, swapped A=w1t B=ea^T) unchanged; h stored into hL in
//   32x32x16-A-FRAGMENT order: hL[ET32:4][KS16:16][lane:64][j:8] with
//   e = ET32*32+(lane&31), k = KS16*16+(lane>>5)*8+j.
//   Store map (derived): ET32=et>>1, lane_r=(g>>1)*32+(et&1)*16+lr,
//   KS16=w*2+ml, j0=(g&1)*4  (int2 store, <=2-way banked).
//   GEMM2: waves = 2 er x 4 cg; wave owns 2 e-tiles(32) x CT col-tiles(32).
//   A = hL (linear-lane ds_read_b128, conflict-free, 2/step vs R16's 8),
//   B = w2t global depth-1 prefetch (bcur[CT]+bnxt[CT] = 16 VGPR).
//   acc[CT][2] f32x16 = 64/32 AGPR. Per-wave LDS reads HALVED (32 KB).
// Register law honored: 64 AGPR + 24 VGPR prefetch+a2 << 128 cap.
// C/D: col=lane&31 (colo), row=(reg&3)+8*(reg>>2)+4*(lane>>5) (e_local).
// o-duplicate lanes (l^16; +l^8 for OUTC=8) pair-summed via shfl_xor.
// Output: msg[e][o] f32 coalesced (no atomics).
template <int N2, int OUTC>
__global__ __launch_bounds__(512, 4) void edge_kernel(
    const float* __restrict__ x, const int* __restrict__ ei,
    const short* __restrict__ eab, const short* __restrict__ w1t,
    const float* __restrict__ b1, const short* __restrict__ w2t,
    const float* __restrict__ b2, float* __restrict__ msg) {
  constexpr int WCG = N2 / 4;                   // cols per col-group: 64 / 32
  constexpr int CT = WCG / 32;                  // 32-col tiles per wave: 2 / 1
  constexpr int LOGO = (OUTC == 16) ? 4 : 3;
  constexpr int PADO = OUTC + 1;                // 17 / 9
  constexpr int PARTSZ = 4 * 128 * PADO * 4;    // 34816 / 18432
  constexpr int XSOFF = (PARTSZ > 65536) ? PARTSZ : 65536;
  __shared__ alignas(16) char smem[XSOFF + 128 * 20 * 4];
  short* const hB = (short*)smem;               // 64 KB fragment-ordered h
  float* const partial = (float*)smem;          // overlays hB after GEMM2
  float* const xs = (float*)(smem + XSOFF);     // x[src] [128][20] f32

  const int tid = threadIdx.x;
  const int w = tid >> 6;
  const int lane = tid & 63;
  const int g = lane >> 4;
  const int lr = lane & 15;
  const int e0 = blockIdx.x * 128;
  const int er = w >> 2;   // e-group: ET32 in {er*2, er*2+1}
  const int cg = w & 3;    // col-group: cols [cg*WCG, +WCG)

  // ---- stage x[src] tile [128][20] f32 ----
  const int eR = tid >> 2;
  const int qR = tid & 3;
  {
    int s = ei[e0 + eR];
    float4 v = *(const float4*)(x + (size_t)s * 16 + qR * 4);
    *(float4*)(xs + eR * 20 + qR * 4) = v;
  }

  // ---- GEMM1 frags: wave w computes h k-rows [w*32, +32) for all 128 edges
  bf16x8 aw[2];
#pragma unroll
  for (int ml = 0; ml < 2; ++ml)
    aw[ml] = *(const bf16x8*)(w1t + ((w * 2 + ml) * 16 + lr) * 32 + g * 8);
  bf16x8 be[8];
#pragma unroll
  for (int et = 0; et < 8; ++et) {
    if (g < 2)
      be[et] = *(const bf16x8*)(eab + (size_t)(e0 + et * 16 + lr) * 16 + g * 8);
    else
      be[et] = (bf16x8){0, 0, 0, 0, 0, 0, 0, 0};
  }

  // ---- GEMM1: acc1[ml][et] -> h[k=(w*2+ml)*16+g*4+r][e=et*16+lr] ----
  f32x4 acc1[2][8];
#pragma unroll
  for (int ml = 0; ml < 2; ++ml)
#pragma unroll
    for (int et = 0; et < 8; ++et) acc1[ml][et] = (f32x4){0.f, 0.f, 0.f, 0.f};
#pragma unroll
  for (int et = 0; et < 8; ++et)
#pragma unroll
    for (int ml = 0; ml < 2; ++ml)
      acc1[ml][et] = __builtin_amdgcn_mfma_f32_16x16x32_bf16(aw[ml], be[et], acc1[ml][et], 0, 0, 0);

  // ---- h = relu(+b1) -> hL in 32x32x16-A-fragment order ----
  // writer k=(w*2+ml)*16+g*4+r, e=et*16+lr ->
  //   ET32=et>>1, KS16=w*2+ml, lane_r=(g>>1)*32+(et&1)*16+lr, j=(g&1)*4+r
#pragma unroll
  for (int ml = 0; ml < 2; ++ml) {
    const int KS16 = w * 2 + ml;
    const int lh = g >> 1;
    const int j0 = (g & 1) * 4;
    float4 bb1 = *(const float4*)(b1 + KS16 * 16 + g * 4);
#pragma unroll
    for (int et = 0; et < 8; ++et) {
      float v0 = fmaxf(acc1[ml][et][0] + bb1.x, 0.f);
      float v1 = fmaxf(acc1[ml][et][1] + bb1.y, 0.f);
      float v2 = fmaxf(acc1[ml][et][2] + bb1.z, 0.f);
      float v3 = fmaxf(acc1[ml][et][3] + bb1.w, 0.f);
      int2 pw; pw.x = (int)cvtpk(v0, v1); pw.y = (int)cvtpk(v2, v3);
      int lane_r = lh * 32 + (et & 1) * 16 + lr;
      *(int2*)(hB + (((et >> 1) * 16 + KS16) * 64 + lane_r) * 8 + j0) = pw;
    }
  }

  // ---- GEMM2 B-frags for ks16=0: issue before barrier (hides under wait) ----
  // B[k][col]: col=lane&31, k=KS16*16+(lane>>5)*8+j
  const int colo_l = cg * WCG + (lane & 31);
  const short* w2b = w2t + (size_t)colo_l * 256 + (lane >> 5) * 8;
  bf16x8 bcur[CT];
#pragma unroll
  for (int ct = 0; ct < CT; ++ct)
    bcur[ct] = *(const bf16x8*)(w2b + ct * 32 * 256);
  __syncthreads();

  // ---- GEMM2: acc[ct][et2] = msg_pre[e][colo] over K=256 (16 steps) ----
  f32x16 acc[CT][2];
#pragma unroll
  for (int ct = 0; ct < CT; ++ct)
#pragma unroll
    for (int t2 = 0; t2 < 2; ++t2)
#pragma unroll
      for (int r = 0; r < 16; ++r) acc[ct][t2][r] = 0.f;
#pragma unroll
  for (int ks = 0; ks < 16; ++ks) {
    bf16x8 bnxt[CT];
    if (ks < 15) {
#pragma unroll
      for (int ct = 0; ct < CT; ++ct)
        bnxt[ct] = *(const bf16x8*)(w2b + ct * 32 * 256 + (ks + 1) * 16);
    }
    bf16x8 a2[2];
#pragma unroll
    for (int t2 = 0; t2 < 2; ++t2)
      a2[t2] = *(const bf16x8*)(hB + (((er * 2 + t2) * 16 + ks) * 64 + lane) * 8);
#pragma unroll
    for (int ct = 0; ct < CT; ++ct)
#pragma unroll
      for (int t2 = 0; t2 < 2; ++t2)
        acc[ct][t2] = __builtin_amdgcn_mfma_f32_32x32x16_bf16(a2[t2], bcur[ct], acc[ct][t2], 0, 0, 0);
    if (ks < 15) {
#pragma unroll
      for (int ct = 0; ct < CT; ++ct) bcur[ct] = bnxt[ct];
    }
  }
  __syncthreads();  // all hL reads done -> partial may overlay

  // ---- epilogue: bilinear in registers -> partial[slot=cg][e][o] ----
  {
    const int o = lane & (OUTC - 1);
    float b2c[CT];
    int iv[CT];
#pragma unroll
    for (int ct = 0; ct < CT; ++ct) {
      int colo = cg * WCG + ct * 32 + (lane & 31);
      b2c[ct] = b2[colo];
      iv[ct] = colo >> LOGO;
    }
#pragma unroll
    for (int t2 = 0; t2 < 2; ++t2) {
#pragma unroll
      for (int reg = 0; reg < 16; ++reg) {
        int e = (er * 2 + t2) * 32 + (reg & 3) + ((reg >> 2) * 8) + ((lane >> 5) * 4);
        float m = 0.f;
#pragma unroll
        for (int ct = 0; ct < CT; ++ct)
          m += (acc[ct][t2][reg] + b2c[ct]) * xs[e * 20 + iv[ct]];
        if (OUTC == 8) m += __shfl_xor(m, 8, 64);  // i-parity fold (lane bit3)
        m += __shfl_xor(m, 16, 64);                // i-parity fold (lane bit4)
        partial[((size_t)cg * 128 + e) * PADO + o] = m;
      }
    }
  }
  __syncthreads();

  // ---- cross-cg reduce -> coalesced msg store ----
  if (qR * 4 < OUTC) {
    float v[4];
#pragma unroll
    for (int j = 0; j < 4; ++j) {
      int o = qR * 4 + j;
      float s = 0.f;
#pragma unroll
      for (int sl = 0; sl < 4; ++sl) s += partial[((size_t)sl * 128 + eR) * PADO + o];
      v[j] = s;
    }
    *(float4*)(msg + (size_t)(e0 + eR) * OUTC + qR * 4) =
        (float4){v[0], v[1], v[2], v[3]};
  }
}

// x_out = relu(gather-mean(msg over CSR) + x_in @ root + bias)
template <int OUTC>
__global__ __launch_bounds__(256) void node_csr(
    const float* __restrict__ xin, const float* __restrict__ msg,
    const int* __restrict__ off, const int* __restrict__ eidx,
    const float* __restrict__ root, const float* __restrict__ bias,
    float* __restrict__ xout) {
  constexpr int Q = OUTC / 4;  // 4 / 2
  __shared__ float rootL[16 * OUTC];
  __shared__ float biasL[OUTC];
  int tid = threadIdx.x;
  if (tid < 16 * OUTC) rootL[tid] = root[tid];
  if (tid < OUTC) biasL[tid] = bias[tid];
  __syncthreads();
  int n = blockIdx.x * (256 / Q) + tid / Q;
  int q = tid & (Q - 1);
  int o0 = off[n], o1 = off[n + 1];
  const float4* msg4 = (const float4*)msg;
  float s[4] = {0.f, 0.f, 0.f, 0.f};
  for (int i = o0; i < o1; ++i) {
    int e = eidx[i];
    float4 v = msg4[(size_t)e * Q + q];
    s[0] += v.x; s[1] += v.y; s[2] += v.z; s[3] += v.w;
  }
  float inv = 1.0f / fmaxf((float)(o1 - o0), 1.0f);
  float xi[16];
#pragma unroll
  for (int i = 0; i < 4; ++i) {
    float4 v = ((const float4*)(xin + (size_t)n * 16))[i];
    xi[4 * i] = v.x; xi[4 * i + 1] = v.y; xi[4 * i + 2] = v.z; xi[4 * i + 3] = v.w;
  }
  float r[4];
#pragma unroll
  for (int j = 0; j < 4; ++j) {
    int o = q * 4 + j;
    float a = s[j] * inv + biasL[o];
#pragma unroll
    for (int i = 0; i < 16; ++i) a += xi[i] * rootL[i * OUTC + o];
    r[j] = fmaxf(a, 0.f);
  }
  *(float4*)(xout + (size_t)n * OUTC + q * 4) = (float4){r[0], r[1], r[2], r[3]};
}

__global__ __launch_bounds__(256) void final_kernel(
    const float* __restrict__ x2, const int* __restrict__ ei,
    const float* __restrict__ fcw, const float* __restrict__ fcb,
    float* __restrict__ out) {
  int e = blockIdx.x * 256 + threadIdx.x;
  int s = ei[e], d = ei[NE + e];
  float acc = fcb[0];
  const float* xsr = x2 + (size_t)s * 8;
  const float* xdr = x2 + (size_t)d * 8;
#pragma unroll
  for (int c = 0; c < 8; ++c) acc += xsr[c] * fcw[c];
#pragma unroll
  for (int c = 0; c < 8; ++c) acc += xdr[c] * fcw[8 + c];
  out[e] = 1.0f / (1.0f + __expf(-acc));
}

extern "C" void kernel_launch(void* const* d_in, const int* in_sizes, int n_in,
                              void* d_out, int out_size, void* d_ws, size_t ws_size,
                              hipStream_t stream) {
  const float* x      = (const float*)d_in[0];
  const int*   ei     = (const int*)d_in[1];
  const float* ea     = (const float*)d_in[2];
  const float* w1_0   = (const float*)d_in[3];
  const float* b1_0   = (const float*)d_in[4];
  const float* w2_0   = (const float*)d_in[5];
  const float* b2_0   = (const float*)d_in[6];
  const float* root_0 = (const float*)d_in[7];
  const float* bias_0 = (const float*)d_in[8];
  const float* w1_1   = (const float*)d_in[9];
  const float* b1_1   = (const float*)d_in[10];
  const float* w2_1   = (const float*)d_in[11];
  const float* b2_1   = (const float*)d_in[12];
  const float* root_1 = (const float*)d_in[13];
  const float* bias_1 = (const float*)d_in[14];
  const float* fc_w   = (const float*)d_in[15];
  const float* fc_b   = (const float*)d_in[16];
  float* out = (float*)d_out;

  char* ws = (char*)d_ws;
  int*   off    = (int*)(ws);                          // 65537 ints
  int*   cursor = (int*)(ws + (512u << 10));           // 256KB (doubles as cnt32)
  int*   bsum   = (int*)(ws + (768u << 10));           // 1KB
  short* w1t0   = (short*)(ws + (1u << 20) + 16384);
  short* w1t1   = w1t0 + 8192;
  short* w2t0   = w1t1 + 8192;
  short* w2t1   = w2t0 + 65536;
  float* x1     = (float*)(ws + (2u << 20));           // 4 MB
  float* x2     = (float*)(ws + (6u << 20));           // 2 MB
  int*   eidx   = (int*)(ws + (8u << 20));             // 1 MB
  short* eab    = (short*)(ws + (9u << 20));           // 8 MB
  float* msg    = (float*)(ws + (17u << 20));          // 16 MB (shared L0/L1)

  int* cnt32 = cursor;  // histogram; scan_kernel rewrites cursor = off

  hipMemsetAsync(cnt32, 0, (size_t)NN * 4, stream);
  prep_all<<<NE * 16 / 256, 256, 0, stream>>>(ea, eab, w1_0, w1_1, w2_0, w2_1,
                                              w1t0, w1t1, w2t0, w2t1, ei, cnt32);
  scan1_kernel<<<256, 256, 0, stream>>>(cnt32, bsum);
  scan_kernel<<<256, 256, 0, stream>>>(cnt32, bsum, off, cursor);
  scatter_kernel<<<NE / 256, 256, 0, stream>>>(ei, cursor, eidx);

  edge_kernel<256, 16><<<NE / 128, 512, 0, stream>>>(
      x, ei, eab, w1t0, b1_0, w2t0, b2_0, msg);
  node_csr<16><<<NN * 4 / 256, 256, 0, stream>>>(x, msg, off, eidx, root_0, bias_0, x1);
  edge_kernel<128, 8><<<NE / 128, 512, 0, stream>>>(
      x1, ei, eab, w1t1, b1_1, w2t1, b2_1, msg);
  node_csr<8><<<NN * 2 / 256, 256, 0, stream>>>(x1, msg, off, eidx, root_1, bias_1, x2);
  final_kernel<<<NE / 256, 256, 0, stream>>>(x2, ei, fc_w, fc_b, out);
}

// Round 19
// 160.404 us; speedup vs baseline: 1.4044x; 1.2676x over previous
//
#include <hip/hip_runtime.h>
#include <stdint.h>

#define NN 65536
#define NE 262144

typedef __attribute__((ext_vector_type(8))) short bf16x8;
typedef __attribute__((ext_vector_type(4))) float f32x4;

__device__ __forceinline__ short f2bf(float f) {
  union { float f; uint32_t u; } v; v.f = f;
  uint32_t u = v.u + 0x7fffu + ((v.u >> 16) & 1u);
  return (short)(u >> 16);
}
__device__ __forceinline__ uint32_t cvtpk(float lo, float hi) {
  uint32_t r;
  asm("v_cvt_pk_bf16_f32 %0, %1, %2" : "=v"(r) : "v"(lo), "v"(hi));
  return r;
}

// Merged prep (per-EDGE threads: 1024 blocks, was 16384): eab bf16 (k<16
// zero-padded, 32B/thread coalesced stores), transposed bf16 weights, dst
// histogram into cnt32 (65536 counters; R15: 256-counter atomics serialize).
__global__ __launch_bounds__(256) void prep_all(
    const float* __restrict__ ea, short* __restrict__ eab,
    const float* __restrict__ w1_0, const float* __restrict__ w1_1,
    const float* __restrict__ w2_0, const float* __restrict__ w2_1,
    short* __restrict__ w1t0, short* __restrict__ w1t1,
    short* __restrict__ w2t0, short* __restrict__ w2t1,
    const int* __restrict__ ei, int* __restrict__ cnt32) {
  int idx = blockIdx.x * 256 + threadIdx.x;  // grid = NE/256 (idx < NE exactly)
  {
    const float* ep = ea + (size_t)idx * 10;
    uint32_t u[8];
#pragma unroll
    for (int j = 0; j < 5; ++j) {
      float2 v = *(const float2*)(ep + j * 2);
      u[j] = cvtpk(v.x, v.y);
    }
    u[5] = u[6] = u[7] = 0u;
    int4* dst = (int4*)(eab + (size_t)idx * 16);
    dst[0] = make_int4((int)u[0], (int)u[1], (int)u[2], (int)u[3]);
    dst[1] = make_int4((int)u[4], (int)u[5], (int)u[6], (int)u[7]);
  }
  atomicAdd(&cnt32[ei[NE + idx]], 1);
  if (idx < 65536) {
    if (idx < 8192) {
      int n = idx >> 5, k = idx & 31;
      w1t0[idx] = (k < 10) ? f2bf(w1_0[k * 256 + n]) : (short)0;
      w1t1[idx] = (k < 10) ? f2bf(w1_1[k * 256 + n]) : (short)0;
    }
    if (idx < 32768) {
      int n = idx >> 8, k = idx & 255;
      w2t1[idx] = f2bf(w2_1[k * 128 + n]);
    }
    {
      int n = idx >> 8, k = idx & 255;
      w2t0[idx] = f2bf(w2_0[k * 256 + n]);
    }
  }
}

// bsum[b] = sum of cnt32[b*256 .. +255]  (tree reduction, no atomics)
__global__ __launch_bounds__(256) void scan1_kernel(const int* __restrict__ cnt32,
                                                    int* __restrict__ bsum) {
  __shared__ int sd[256];
  int t = threadIdx.x, b = blockIdx.x;
  sd[t] = cnt32[b * 256 + t];
  __syncthreads();
  for (int s = 128; s > 0; s >>= 1) {
    if (t < s) sd[t] += sd[t + s];
    __syncthreads();
  }
  if (t == 0) bsum[b] = sd[0];
}

// Merged scan2+scan3 -> global exclusive offsets.
__global__ __launch_bounds__(256) void scan_kernel(
    const int* __restrict__ cnt32, const int* __restrict__ bsum,
    int* __restrict__ off, int* __restrict__ cursor) {
  __shared__ int sb[256];
  __shared__ int sd[256];
  int t = threadIdx.x, b = blockIdx.x;
  int idx = b * 256 + t;
  int vb = bsum[t];
  int vd = cnt32[idx];
  sb[t] = vb;
  sd[t] = vd;
  __syncthreads();
  for (int st = 1; st < 256; st <<= 1) {
    int xb = (t >= st) ? sb[t - st] : 0;
    int xd = (t >= st) ? sd[t - st] : 0;
    __syncthreads();
    sb[t] += xb;
    sd[t] += xd;
    __syncthreads();
  }
  int boffb = sb[b] - bsum[b];
  int o = boffb + sd[t] - vd;
  off[idx] = o;
  cursor[idx] = o;
  if (b == 0 && t == 0) off[65536] = NE;
}

__global__ __launch_bounds__(256) void scatter_kernel(const int* __restrict__ ei,
                                                      int* __restrict__ cursor,
                                                      int* __restrict__ eidx) {
  int e = blockIdx.x * 256 + threadIdx.x;
  int pos = atomicAdd(&cursor[ei[NE + e]], 1);
  eidx[pos] = e;
}

// ---------------- fused edge kernel: 128 edges/block, 8 waves ----------------
// R16 measured-best config (57.9us) + T5 setprio around MFMA clusters:
//   GEMM1 swapped (A=w1t, B=ea^T); h stored into hL in MFMA-fragment order
//     hL[(et*8+ks)*64+lane][8] -> GEMM2 A-reads linear-in-lane (conflict-free).
//   GEMM2: A = hL (LDS), B = w2t (global, depth-1 prefetch; ks=0 preloaded
//     under the h-store). Wave w owns cols [w*WCOLS,+WCOLS) across ALL 8
//     e-tiles = 16 MFMAs per load window (R13/R18: this density is the lever;
//     halving it loses 1.5-2x regardless of occupancy or LDS read volume).
// Register law: acc(64 AGPR) + prefetch(16-32) + addressing <= 128 under
//   __launch_bounds__(512,4) -- violations spill (WRITE_SIZE balloons).
// OUTC=8: lanes lr / lr^8 share o (different i parity) -> __shfl_xor(m,8).
// Output: msg[e][o] f32 coalesced (no atomics).
template <int N2, int OUTC>
__global__ __launch_bounds__(512, 4) void edge_kernel(
    const float* __restrict__ x, const int* __restrict__ ei,
    const short* __restrict__ eab, const short* __restrict__ w1t,
    const float* __restrict__ b1, const short* __restrict__ w2t,
    const float* __restrict__ b2, float* __restrict__ msg) {
  constexpr int WCOLS = N2 / 8;                 // 32 / 16
  constexpr int NT2 = WCOLS / 16;               // 2 / 1
  constexpr int LOGO = (OUTC == 16) ? 4 : 3;
  constexpr int PADO = OUTC + 1;                // 17 / 9
  constexpr int PARTSZ = 8 * 128 * PADO * 4;    // 69632 / 36864
  constexpr int XSOFF = (PARTSZ > 65536) ? PARTSZ : 65536;
  __shared__ alignas(16) char smem[XSOFF + 128 * 20 * 4];
  short* const hB = (short*)smem;               // 64 KB fragment-ordered h
  float* const partial = (float*)smem;          // overlays hB after GEMM2
  float* const xs = (float*)(smem + XSOFF);     // x[src] [128][20] f32

  const int tid = threadIdx.x;
  const int w = tid >> 6;
  const int lane = tid & 63;
  const int g = lane >> 4;
  const int lr = lane & 15;
  const int e0 = blockIdx.x * 128;

  // ---- stage x[src] tile [128][20] f32 ----
  const int eR = tid >> 2;
  const int qR = tid & 3;
  {
    int s = ei[e0 + eR];
    float4 v = *(const float4*)(x + (size_t)s * 16 + qR * 4);
    *(float4*)(xs + eR * 20 + qR * 4) = v;
  }

  // ---- GEMM1 frags: wave w computes h k-rows [w*32, +32) for all 128 edges
  bf16x8 aw[2];
#pragma unroll
  for (int ml = 0; ml < 2; ++ml)
    aw[ml] = *(const bf16x8*)(w1t + ((w * 2 + ml) * 16 + lr) * 32 + g * 8);
  bf16x8 be[8];
#pragma unroll
  for (int et = 0; et < 8; ++et) {
    if (g < 2)
      be[et] = *(const bf16x8*)(eab + (size_t)(e0 + et * 16 + lr) * 16 + g * 8);
    else
      be[et] = (bf16x8){0, 0, 0, 0, 0, 0, 0, 0};
  }

  // ---- GEMM1: acc1[ml][et] -> h[k=(w*2+ml)*16+g*4+r][e=et*16+lr] ----
  f32x4 acc1[2][8];
#pragma unroll
  for (int ml = 0; ml < 2; ++ml)
#pragma unroll
    for (int et = 0; et < 8; ++et) acc1[ml][et] = (f32x4){0.f, 0.f, 0.f, 0.f};
  __builtin_amdgcn_s_setprio(1);
#pragma unroll
  for (int et = 0; et < 8; ++et)
#pragma unroll
    for (int ml = 0; ml < 2; ++ml)
      acc1[ml][et] = __builtin_amdgcn_mfma_f32_16x16x32_bf16(aw[ml], be[et], acc1[ml][et], 0, 0, 0);
  __builtin_amdgcn_s_setprio(0);

  // ---- GEMM2 B-frags for ks=0: issue NOW so latency hides under h-store ----
  bf16x8 bcur[NT2];
#pragma unroll
  for (int nt = 0; nt < NT2; ++nt) {
    int colo = w * WCOLS + nt * 16 + lr;
    bcur[nt] = *(const bf16x8*)(w2t + colo * 256 + g * 8);
  }

  // ---- h = relu(+b1) -> hL fragment-ordered (ks = w for this wave) ----
  // store k = (w*2+ml)*16+g*4+r  ->  reader (ks=w, rg=ml*2+(g>>1), j=(g&1)*4+r)
#pragma unroll
  for (int ml = 0; ml < 2; ++ml) {
    const int K16 = w * 2 + ml;
    const int rg = ml * 2 + (g >> 1);
    const int j0 = (g & 1) * 4;
    float4 bb1 = *(const float4*)(b1 + K16 * 16 + g * 4);
#pragma unroll
    for (int et = 0; et < 8; ++et) {
      float v0 = fmaxf(acc1[ml][et][0] + bb1.x, 0.f);
      float v1 = fmaxf(acc1[ml][et][1] + bb1.y, 0.f);
      float v2 = fmaxf(acc1[ml][et][2] + bb1.z, 0.f);
      float v3 = fmaxf(acc1[ml][et][3] + bb1.w, 0.f);
      int2 pw; pw.x = (int)cvtpk(v0, v1); pw.y = (int)cvtpk(v2, v3);
      *(int2*)(hB + ((et * 8 + w) * 64 + rg * 16 + lr) * 8 + j0) = pw;
    }
  }
  __syncthreads();

  // ---- GEMM2: acc[mt][nt] over all 8 e-tiles; A = hL (linear-lane reads,
  //      conflict-free), B = w2t depth-1 prefetch; two 4-e-tile halves ----
  f32x4 acc[8][NT2];
#pragma unroll
  for (int mt = 0; mt < 8; ++mt)
#pragma unroll
    for (int nt = 0; nt < NT2; ++nt) acc[mt][nt] = (f32x4){0.f, 0.f, 0.f, 0.f};
#pragma unroll
  for (int ks = 0; ks < 8; ++ks) {
    bf16x8 bnxt[NT2];
    if (ks < 7) {
#pragma unroll
      for (int nt = 0; nt < NT2; ++nt) {
        int colo = w * WCOLS + nt * 16 + lr;
        bnxt[nt] = *(const bf16x8*)(w2t + colo * 256 + (ks + 1) * 32 + g * 8);
      }
    }
#pragma unroll
    for (int hf = 0; hf < 2; ++hf) {
      bf16x8 a2[4];
#pragma unroll
      for (int m4 = 0; m4 < 4; ++m4)
        a2[m4] = *(const bf16x8*)(hB + (((hf * 4 + m4) * 8 + ks) * 64 + lane) * 8);
      __builtin_amdgcn_s_setprio(1);
#pragma unroll
      for (int nt = 0; nt < NT2; ++nt)
#pragma unroll
        for (int m4 = 0; m4 < 4; ++m4)
          acc[hf * 4 + m4][nt] =
              __builtin_amdgcn_mfma_f32_16x16x32_bf16(a2[m4], bcur[nt], acc[hf * 4 + m4][nt], 0, 0, 0);
      __builtin_amdgcn_s_setprio(0);
    }
    if (ks < 7) {
#pragma unroll
      for (int nt = 0; nt < NT2; ++nt) bcur[nt] = bnxt[nt];
    }
  }
  __syncthreads();  // all hL reads done -> partial may overlay

  // ---- epilogue: bilinear in registers -> partial[slot=w][e][o] ----
  {
    const int o = lr & (OUTC - 1);
    float b2c[NT2];
    int iv[NT2];
#pragma unroll
    for (int nt = 0; nt < NT2; ++nt) {
      int colo = w * WCOLS + nt * 16 + lr;
      b2c[nt] = b2[colo];
      iv[nt] = colo >> LOGO;
    }
#pragma unroll
    for (int mt = 0; mt < 8; ++mt)
#pragma unroll
      for (int r = 0; r < 4; ++r) {
        int e = mt * 16 + g * 4 + r;
        float m = 0.f;
#pragma unroll
        for (int nt = 0; nt < NT2; ++nt)
          m += (acc[mt][nt][r] + b2c[nt]) * xs[e * 20 + iv[nt]];
        if (OUTC == 8) m += __shfl_xor(m, 8, 64);  // sum lr-halves (i parity)
        partial[((size_t)w * 128 + e) * PADO + o] = m;
      }
  }
  __syncthreads();

  // ---- cross-slot reduce -> coalesced msg store ----
  if (qR * 4 < OUTC) {
    float v[4];
#pragma unroll
    for (int j = 0; j < 4; ++j) {
      int o = qR * 4 + j;
      float s = 0.f;
#pragma unroll
      for (int sl = 0; sl < 8; ++sl) s += partial[((size_t)sl * 128 + eR) * PADO + o];
      v[j] = s;
    }
    *(float4*)(msg + (size_t)(e0 + eR) * OUTC + qR * 4) =
        (float4){v[0], v[1], v[2], v[3]};
  }
}

// x_out = relu(gather-mean(msg over CSR) + x_in @ root + bias)
template <int OUTC>
__global__ __launch_bounds__(256) void node_csr(
    const float* __restrict__ xin, const float* __restrict__ msg,
    const int* __restrict__ off, const int* __restrict__ eidx,
    const float* __restrict__ root, const float* __restrict__ bias,
    float* __restrict__ xout) {
  constexpr int Q = OUTC / 4;  // 4 / 2
  __shared__ float rootL[16 * OUTC];
  __shared__ float biasL[OUTC];
  int tid = threadIdx.x;
  if (tid < 16 * OUTC) rootL[tid] = root[tid];
  if (tid < OUTC) biasL[tid] = bias[tid];
  __syncthreads();
  int n = blockIdx.x * (256 / Q) + tid / Q;
  int q = tid & (Q - 1);
  int o0 = off[n], o1 = off[n + 1];
  const float4* msg4 = (const float4*)msg;
  float s[4] = {0.f, 0.f, 0.f, 0.f};
  for (int i = o0; i < o1; ++i) {
    int e = eidx[i];
    float4 v = msg4[(size_t)e * Q + q];
    s[0] += v.x; s[1] += v.y; s[2] += v.z; s[3] += v.w;
  }
  float inv = 1.0f / fmaxf((float)(o1 - o0), 1.0f);
  float xi[16];
#pragma unroll
  for (int i = 0; i < 4; ++i) {
    float4 v = ((const float4*)(xin + (size_t)n * 16))[i];
    xi[4 * i] = v.x; xi[4 * i + 1] = v.y; xi[4 * i + 2] = v.z; xi[4 * i + 3] = v.w;
  }
  float r[4];
#pragma unroll
  for (int j = 0; j < 4; ++j) {
    int o = q * 4 + j;
    float a = s[j] * inv + biasL[o];
#pragma unroll
    for (int i = 0; i < 16; ++i) a += xi[i] * rootL[i * OUTC + o];
    r[j] = fmaxf(a, 0.f);
  }
  *(float4*)(xout + (size_t)n * OUTC + q * 4) = (float4){r[0], r[1], r[2], r[3]};
}

__global__ __launch_bounds__(256) void final_kernel(
    const float* __restrict__ x2, const int* __restrict__ ei,
    const float* __restrict__ fcw, const float* __restrict__ fcb,
    float* __restrict__ out) {
  int e = blockIdx.x * 256 + threadIdx.x;
  int s = ei[e], d = ei[NE + e];
  float acc = fcb[0];
  const float* xsr = x2 + (size_t)s * 8;
  const float* xdr = x2 + (size_t)d * 8;
#pragma unroll
  for (int c = 0; c < 8; ++c) acc += xsr[c] * fcw[c];
#pragma unroll
  for (int c = 0; c < 8; ++c) acc += xdr[c] * fcw[8 + c];
  out[e] = 1.0f / (1.0f + __expf(-acc));
}

extern "C" void kernel_launch(void* const* d_in, const int* in_sizes, int n_in,
                              void* d_out, int out_size, void* d_ws, size_t ws_size,
                              hipStream_t stream) {
  const float* x      = (const float*)d_in[0];
  const int*   ei     = (const int*)d_in[1];
  const float* ea     = (const float*)d_in[2];
  const float* w1_0   = (const float*)d_in[3];
  const float* b1_0   = (const float*)d_in[4];
  const float* w2_0   = (const float*)d_in[5];
  const float* b2_0   = (const float*)d_in[6];
  const float* root_0 = (const float*)d_in[7];
  const float* bias_0 = (const float*)d_in[8];
  const float* w1_1   = (const float*)d_in[9];
  const float* b1_1   = (const float*)d_in[10];
  const float* w2_1   = (const float*)d_in[11];
  const float* b2_1   = (const float*)d_in[12];
  const float* root_1 = (const float*)d_in[13];
  const float* bias_1 = (const float*)d_in[14];
  const float* fc_w   = (const float*)d_in[15];
  const float* fc_b   = (const float*)d_in[16];
  float* out = (float*)d_out;

  char* ws = (char*)d_ws;
  int*   off    = (int*)(ws);                          // 65537 ints
  int*   cursor = (int*)(ws + (512u << 10));           // 256KB (doubles as cnt32)
  int*   bsum   = (int*)(ws + (768u << 10));           // 1KB
  short* w1t0   = (short*)(ws + (1u << 20) + 16384);
  short* w1t1   = w1t0 + 8192;
  short* w2t0   = w1t1 + 8192;
  short* w2t1   = w2t0 + 65536;
  float* x1     = (float*)(ws + (2u << 20));           // 4 MB
  float* x2     = (float*)(ws + (6u << 20));           // 2 MB
  int*   eidx   = (int*)(ws + (8u << 20));             // 1 MB
  short* eab    = (short*)(ws + (9u << 20));           // 8 MB
  float* msg    = (float*)(ws + (17u << 20));          // 16 MB (shared L0/L1)

  int* cnt32 = cursor;  // histogram; scan_kernel rewrites cursor = off

  hipMemsetAsync(cnt32, 0, (size_t)NN * 4, stream);
  prep_all<<<NE / 256, 256, 0, stream>>>(ea, eab, w1_0, w1_1, w2_0, w2_1,
                                         w1t0, w1t1, w2t0, w2t1, ei, cnt32);
  scan1_kernel<<<256, 256, 0, stream>>>(cnt32, bsum);
  scan_kernel<<<256, 256, 0, stream>>>(cnt32, bsum, off, cursor);
  scatter_kernel<<<NE / 256, 256, 0, stream>>>(ei, cursor, eidx);

  edge_kernel<256, 16><<<NE / 128, 512, 0, stream>>>(
      x, ei, eab, w1t0, b1_0, w2t0, b2_0, msg);
  node_csr<16><<<NN * 4 / 256, 256, 0, stream>>>(x, msg, off, eidx, root_0, bias_0, x1);
  edge_kernel<128, 8><<<NE / 128, 512, 0, stream>>>(
      x1, ei, eab, w1t1, b1_1, w2t1, b2_1, msg);
  node_csr<8><<<NN * 2 / 256, 256, 0, stream>>>(x1, msg, off, eidx, root_1, bias_1, x2);
  final_kernel<<<NE / 256, 256, 0, stream>>>(x2, ei, fc_w, fc_b, out);
}